// Round 2
// baseline (547.568 us; speedup 1.0000x reference)
//
#include <hip/hip_runtime.h>

#define DEVI __device__ __forceinline__

typedef short bf16x8 __attribute__((ext_vector_type(8)));
typedef float f32x4 __attribute__((ext_vector_type(4)));

constexpr int Bb = 8, TX = 1024, TC = 2048, CC = 512, NH = 8, HD = 64;

// fp32 -> bf16 round-to-nearest-even (values here are well-behaved, no NaN/Inf)
DEVI unsigned short f2bf(float f) {
  union { float f; unsigned u; } v; v.f = f;
  return (unsigned short)((v.u + 0x7FFFu + ((v.u >> 16) & 1u)) >> 16);
}

DEVI f32x4 mfma16(bf16x8 a, bf16x8 b, f32x4 c) {
  return __builtin_amdgcn_mfma_f32_16x16x32_bf16(a, b, c, 0, 0, 0);
}

DEVI f32x4 zero4() { f32x4 z = {0.f, 0.f, 0.f, 0.f}; return z; }

// ---------------------------------------------------------------------------
// NT GEMM: out[r][c] = sum_k A[r][k] * W[c][k] + bias[c]
// A: (M x 512) fp32 row-major.  W: (512 x 512) fp32 row-major (= B^T).
// MODE 0: out bf16, permuted to (b, h, t, d) for attention.  MODE 1: out fp32 (r*512+c).
// 64x64 tile, BK=32, 256 threads = 4 waves in 2x2, each wave 32x32 (2x2 MFMA frags).
// ---------------------------------------------------------------------------
template <int MODE>
__global__ __launch_bounds__(256) void proj_gemm(
    const float* __restrict__ A, const float* __restrict__ W,
    const float* __restrict__ bias, void* __restrict__ outp, int tlog2) {
  // stride 40 shorts (=80B): keeps b128 reads 16B-aligned, spreads rows over banks
  // (k only spans 0..31 here, so stride 40 > 32 is safe)
  __shared__ __align__(16) unsigned short As[64 * 40];
  __shared__ __align__(16) unsigned short Bs[64 * 40];

  const int tid = threadIdx.x;
  const int wid = tid >> 6, l = tid & 63, l15 = l & 15, lhi = l >> 4;
  const int wm = wid >> 1, wn = wid & 1;
  const int mbase = blockIdx.y * 64, nbase = blockIdx.x * 64;
  const int sr = tid >> 2, sc0 = (tid & 3) * 8;

  f32x4 acc[2][2];
#pragma unroll
  for (int i = 0; i < 2; i++)
#pragma unroll
    for (int j = 0; j < 2; j++) acc[i][j] = zero4();

  for (int k0 = 0; k0 < CC; k0 += 32) {
    {
      const float* ap = A + (size_t)(mbase + sr) * CC + k0 + sc0;
      f32x4 f0 = *(const f32x4*)ap;
      f32x4 f1 = *(const f32x4*)(ap + 4);
      bf16x8 va;
#pragma unroll
      for (int i = 0; i < 4; i++) {
        va[i] = (short)f2bf(f0[i]);
        va[i + 4] = (short)f2bf(f1[i]);
      }
      *(bf16x8*)&As[sr * 40 + sc0] = va;

      const float* bp = W + (size_t)(nbase + sr) * CC + k0 + sc0;
      f32x4 g0 = *(const f32x4*)bp;
      f32x4 g1 = *(const f32x4*)(bp + 4);
      bf16x8 vb;
#pragma unroll
      for (int i = 0; i < 4; i++) {
        vb[i] = (short)f2bf(g0[i]);
        vb[i + 4] = (short)f2bf(g1[i]);
      }
      *(bf16x8*)&Bs[sr * 40 + sc0] = vb;
    }
    __syncthreads();

    bf16x8 a0 = *(const bf16x8*)&As[(wm * 32 + l15) * 40 + lhi * 8];
    bf16x8 a1 = *(const bf16x8*)&As[(wm * 32 + 16 + l15) * 40 + lhi * 8];
    bf16x8 b0 = *(const bf16x8*)&Bs[(wn * 32 + l15) * 40 + lhi * 8];
    bf16x8 b1 = *(const bf16x8*)&Bs[(wn * 32 + 16 + l15) * 40 + lhi * 8];
    acc[0][0] = mfma16(a0, b0, acc[0][0]);
    acc[0][1] = mfma16(a0, b1, acc[0][1]);
    acc[1][0] = mfma16(a1, b0, acc[1][0]);
    acc[1][1] = mfma16(a1, b1, acc[1][1]);
    __syncthreads();
  }

#pragma unroll
  for (int mi = 0; mi < 2; mi++)
#pragma unroll
    for (int ni = 0; ni < 2; ni++)
#pragma unroll
      for (int r = 0; r < 4; r++) {
        int grow = mbase + wm * 32 + mi * 16 + 4 * lhi + r;
        int gcol = nbase + wn * 32 + ni * 16 + l15;
        float val = acc[mi][ni][r] + bias[gcol];
        if (MODE == 0) {
          int T = 1 << tlog2;
          int bq = grow >> tlog2, tt = grow & (T - 1);
          int h = gcol >> 6, d = gcol & 63;
          size_t oidx = ((size_t)(bq * NH + h) * T + tt) * HD + d;
          ((unsigned short*)outp)[oidx] = f2bf(val);
        } else {
          ((float*)outp)[(size_t)grow * CC + gcol] = val;
        }
      }
}

// ---------------------------------------------------------------------------
// Flash attention fwd. Block = 4 waves, each wave owns a 16-row q-tile of the
// same (b,h); iterates 64-key tiles with online softmax fully in registers.
// Writes y_pre (fp32, (b,t,c)) and per-row running max m / inverse-sum 1/l.
// ---------------------------------------------------------------------------
__global__ __launch_bounds__(256) void attn_fwd(
    const unsigned short* __restrict__ Qw, const unsigned short* __restrict__ Kw,
    const unsigned short* __restrict__ Vw, float* __restrict__ y_pre,
    float* __restrict__ m_ws, float* __restrict__ il_ws) {
  // vt stride 72 shorts (=144B = 9x16B): k spans 0..63, stride must exceed 64;
  // 144B keeps b128 reads 16B-aligned; rows 36 words apart = 4 banks -> 8-bank spread
  __shared__ __align__(16) unsigned short vt[64 * 72];        // V tile transposed [d][k]
  __shared__ __align__(16) unsigned short plds[4][16 * 72];   // per-wave P tiles [row][key]

  const int tid = threadIdx.x;
  const int wid = tid >> 6, l = tid & 63, l15 = l & 15, lhi = l >> 4;
  const int qg = blockIdx.x, h = blockIdx.y, b = blockIdx.z;
  const int qbase = qg * 64 + wid * 16;

  const unsigned short* Qh = Qw + (size_t)(b * NH + h) * TX * HD;
  const unsigned short* Kh = Kw + (size_t)(b * NH + h) * TC * HD;
  const unsigned short* Vh = Vw + (size_t)(b * NH + h) * TC * HD;

  // Q A-frags (constant over the whole K loop): row=l15, k=8*lhi+e (+32 for second half)
  bf16x8 aq0 = *(const bf16x8*)(Qh + (size_t)(qbase + l15) * HD + lhi * 8);
  bf16x8 aq1 = *(const bf16x8*)(Qh + (size_t)(qbase + l15) * HD + 32 + lhi * 8);

  f32x4 accy[4];
#pragma unroll
  for (int db = 0; db < 4; db++) accy[db] = zero4();
  float mrun[4], lrun[4];
#pragma unroll
  for (int r = 0; r < 4; r++) { mrun[r] = -1e30f; lrun[r] = 0.f; }

  const int vr = tid >> 3, vj = tid & 7, vd0 = vj * 8;

  for (int kt = 0; kt < TC / 64; kt++) {
    const int keyb = kt * 64;

    // stage V tile transposed (global read coalesced; stagger kills bank conflicts)
#pragma unroll
    for (int rr = 0; rr < 64; rr += 32) {
      bf16x8 v = *(const bf16x8*)(Vh + (size_t)(keyb + vr + rr) * HD + vd0);
#pragma unroll
      for (int i = 0; i < 8; i++) {
        int j = (i + vj) & 7;
        vt[(vd0 + j) * 72 + (vr + rr)] = (unsigned short)v[j];
      }
    }

    // QK^T for 4 key-blocks of 16 (K frags straight from global, L1/L2 hot)
    f32x4 s[4];
#pragma unroll
    for (int kb = 0; kb < 4; kb++) {
      const unsigned short* kp = Kh + (size_t)(keyb + kb * 16 + l15) * HD + lhi * 8;
      bf16x8 bk0 = *(const bf16x8*)kp;
      bf16x8 bk1 = *(const bf16x8*)(kp + 32);
      f32x4 a = zero4();
      a = mfma16(aq0, bk0, a);
      a = mfma16(aq1, bk1, a);
      s[kb] = a * 0.125f;  // 1/sqrt(64)
    }

    // online softmax update; rows of reg r live on the 16 lanes of each lhi group
    float mnew[4], scal[4], psum[4];
#pragma unroll
    for (int r = 0; r < 4; r++) {
      float mx = fmaxf(fmaxf(s[0][r], s[1][r]), fmaxf(s[2][r], s[3][r]));
#pragma unroll
      for (int off = 1; off < 16; off <<= 1) mx = fmaxf(mx, __shfl_xor(mx, off));
      mnew[r] = fmaxf(mrun[r], mx);
      scal[r] = __expf(mrun[r] - mnew[r]);
      psum[r] = 0.f;
    }
#pragma unroll
    for (int kb = 0; kb < 4; kb++)
#pragma unroll
      for (int r = 0; r < 4; r++) {
        float p = __expf(s[kb][r] - mnew[r]);
        psum[r] += p;
        plds[wid][(4 * lhi + r) * 72 + kb * 16 + l15] = f2bf(p);
      }
#pragma unroll
    for (int r = 0; r < 4; r++) {
      float ps = psum[r];
#pragma unroll
      for (int off = 1; off < 16; off <<= 1) ps += __shfl_xor(ps, off);
      lrun[r] = lrun[r] * scal[r] + ps;
      mrun[r] = mnew[r];
    }

    __syncthreads();  // vt + plds writes visible

    // rescale accumulator by exp(m_old - m_new)
#pragma unroll
    for (int db = 0; db < 4; db++)
#pragma unroll
      for (int r = 0; r < 4; r++) accy[db][r] *= scal[r];

    // PV: A = P tile (via LDS transpose), B = V tile (transposed in LDS)
    bf16x8 ap0 = *(const bf16x8*)&plds[wid][l15 * 72 + lhi * 8];
    bf16x8 ap1 = *(const bf16x8*)&plds[wid][l15 * 72 + 32 + lhi * 8];
#pragma unroll
    for (int db = 0; db < 4; db++) {
      bf16x8 bv0 = *(const bf16x8*)&vt[(db * 16 + l15) * 72 + lhi * 8];
      bf16x8 bv1 = *(const bf16x8*)&vt[(db * 16 + l15) * 72 + 32 + lhi * 8];
      accy[db] = mfma16(ap0, bv0, accy[db]);
      accy[db] = mfma16(ap1, bv1, accy[db]);
    }
    __syncthreads();  // all reads done before next stage overwrites vt
  }

  float il[4];
#pragma unroll
  for (int r = 0; r < 4; r++) il[r] = 1.f / lrun[r];

#pragma unroll
  for (int db = 0; db < 4; db++)
#pragma unroll
    for (int r = 0; r < 4; r++) {
      int trow = qbase + 4 * lhi + r;
      y_pre[(size_t)(b * TX + trow) * CC + h * HD + db * 16 + l15] = accy[db][r] * il[r];
    }
  if (l15 == 0) {
#pragma unroll
    for (int r = 0; r < 4; r++) {
      int idx = (b * NH + h) * TX + qbase + 4 * lhi + r;
      m_ws[idx] = mrun[r];
      il_ws[idx] = il[r];
    }
  }
}

// ---------------------------------------------------------------------------
// att_mean: recompute QK^T per head, p = exp(s - m) * (1/l), mean over heads.
// Block: 16 q-rows x 64 keys (wave w -> key block w*16).
// ---------------------------------------------------------------------------
__global__ __launch_bounds__(256) void att_mean_k(
    const unsigned short* __restrict__ Qw, const unsigned short* __restrict__ Kw,
    const float* __restrict__ m_ws, const float* __restrict__ il_ws,
    float* __restrict__ attm) {
  const int tid = threadIdx.x;
  const int wid = tid >> 6, l = tid & 63, l15 = l & 15, lhi = l >> 4;
  const int keyb = blockIdx.x * 64 + wid * 16;
  const int qbase = blockIdx.y * 16;
  const int b = blockIdx.z;

  f32x4 am = zero4();
#pragma unroll
  for (int h = 0; h < NH; h++) {
    const unsigned short* Qh = Qw + (size_t)(b * NH + h) * TX * HD;
    const unsigned short* Kh = Kw + (size_t)(b * NH + h) * TC * HD;
    bf16x8 aq0 = *(const bf16x8*)(Qh + (size_t)(qbase + l15) * HD + lhi * 8);
    bf16x8 aq1 = *(const bf16x8*)(Qh + (size_t)(qbase + l15) * HD + 32 + lhi * 8);
    bf16x8 bk0 = *(const bf16x8*)(Kh + (size_t)(keyb + l15) * HD + lhi * 8);
    bf16x8 bk1 = *(const bf16x8*)(Kh + (size_t)(keyb + l15) * HD + 32 + lhi * 8);
    f32x4 a = zero4();
    a = mfma16(aq0, bk0, a);
    a = mfma16(aq1, bk1, a);
    const float* mp = m_ws + (size_t)(b * NH + h) * TX + qbase + 4 * lhi;
    const float* ip = il_ws + (size_t)(b * NH + h) * TX + qbase + 4 * lhi;
#pragma unroll
    for (int r = 0; r < 4; r++) am[r] += __expf(a[r] * 0.125f - mp[r]) * ip[r];
  }
#pragma unroll
  for (int r = 0; r < 4; r++) {
    int trow = qbase + 4 * lhi + r;
    attm[(size_t)(b * TX + trow) * TC + keyb + l15] = am[r] * 0.125f;
  }
}

// ---------------------------------------------------------------------------
extern "C" void kernel_launch(void* const* d_in, const int* in_sizes, int n_in,
                              void* d_out, int out_size, void* d_ws, size_t ws_size,
                              hipStream_t stream) {
  const float* x   = (const float*)d_in[0];
  const float* ctx = (const float*)d_in[1];
  const float* Wq  = (const float*)d_in[2];
  const float* bq  = (const float*)d_in[3];
  const float* Wk  = (const float*)d_in[4];
  const float* bk  = (const float*)d_in[5];
  const float* Wv  = (const float*)d_in[6];
  const float* bv  = (const float*)d_in[7];
  const float* Wo  = (const float*)d_in[8];
  const float* bo  = (const float*)d_in[9];

  float* y_out = (float*)d_out;                       // (B, Tx, C)
  float* attm  = y_out + (size_t)Bb * TX * CC;        // (B, Tx, Tc)

  // workspace layout (all 16B-aligned): ~56.5 MB
  unsigned short* q_ws = (unsigned short*)d_ws;                  // B*NH*TX*HD bf16
  unsigned short* k_ws = q_ws + (size_t)Bb * NH * TX * HD;       // B*NH*TC*HD bf16
  unsigned short* v_ws = k_ws + (size_t)Bb * NH * TC * HD;       // B*NH*TC*HD bf16
  float* m_ws  = (float*)(v_ws + (size_t)Bb * NH * TC * HD);     // B*NH*TX f32
  float* il_ws = m_ws + (size_t)Bb * NH * TX;                    // B*NH*TX f32
  float* y_pre = il_ws + (size_t)Bb * NH * TX;                   // B*TX*CC f32

  proj_gemm<0><<<dim3(CC / 64, (Bb * TX) / 64), 256, 0, stream>>>(x, Wq, bq, q_ws, 10);
  proj_gemm<0><<<dim3(CC / 64, (Bb * TC) / 64), 256, 0, stream>>>(ctx, Wk, bk, k_ws, 11);
  proj_gemm<0><<<dim3(CC / 64, (Bb * TC) / 64), 256, 0, stream>>>(ctx, Wv, bv, v_ws, 11);
  attn_fwd<<<dim3(TX / 64, NH, Bb), 256, 0, stream>>>(q_ws, k_ws, v_ws, y_pre, m_ws, il_ws);
  att_mean_k<<<dim3(TC / 64, TX / 16, Bb), 256, 0, stream>>>(q_ws, k_ws, m_ws, il_ws, attm);
  proj_gemm<1><<<dim3(CC / 64, (Bb * TX) / 64), 256, 0, stream>>>(y_pre, Wo, bo, y_out, 10);
}

// Round 3
// 444.679 us; speedup vs baseline: 1.2314x; 1.2314x over previous
//
#include <hip/hip_runtime.h>

#define DEVI __device__ __forceinline__

typedef short bf16x8 __attribute__((ext_vector_type(8)));
typedef float f32x4 __attribute__((ext_vector_type(4)));

constexpr int Bb = 8, TX = 1024, TC = 2048, CC = 512, NH = 8, HD = 64;

// fp32 -> bf16 round-to-nearest-even (values here are well-behaved, no NaN/Inf)
DEVI unsigned short f2bf(float f) {
  union { float f; unsigned u; } v; v.f = f;
  return (unsigned short)((v.u + 0x7FFFu + ((v.u >> 16) & 1u)) >> 16);
}

DEVI f32x4 mfma16(bf16x8 a, bf16x8 b, f32x4 c) {
  return __builtin_amdgcn_mfma_f32_16x16x32_bf16(a, b, c, 0, 0, 0);
}

DEVI f32x4 zero4() { f32x4 z = {0.f, 0.f, 0.f, 0.f}; return z; }

// ---------------------------------------------------------------------------
// NT GEMM: out[r][c] = sum_k A[r][k] * W[c][k] + bias[c]
// A: (M x 512) fp32 row-major.  W: (512 x 512) fp32 row-major (= B^T).
// MODE 0: out bf16, permuted to (b, h, t, d) for attention.  MODE 1: out fp32 (r*512+c).
// 64x64 tile, BK=32, 256 threads = 4 waves in 2x2, each wave 32x32 (2x2 MFMA frags).
// ---------------------------------------------------------------------------
template <int MODE>
__global__ __launch_bounds__(256) void proj_gemm(
    const float* __restrict__ A, const float* __restrict__ W,
    const float* __restrict__ bias, void* __restrict__ outp, int tlog2) {
  // stride 40 shorts (=80B): keeps b128 reads 16B-aligned, spreads rows over banks
  // (k only spans 0..31 here, so stride 40 > 32 is safe)
  __shared__ __align__(16) unsigned short As[64 * 40];
  __shared__ __align__(16) unsigned short Bs[64 * 40];

  const int tid = threadIdx.x;
  const int wid = tid >> 6, l = tid & 63, l15 = l & 15, lhi = l >> 4;
  const int wm = wid >> 1, wn = wid & 1;
  const int mbase = blockIdx.y * 64, nbase = blockIdx.x * 64;
  const int sr = tid >> 2, sc0 = (tid & 3) * 8;

  f32x4 acc[2][2];
#pragma unroll
  for (int i = 0; i < 2; i++)
#pragma unroll
    for (int j = 0; j < 2; j++) acc[i][j] = zero4();

  for (int k0 = 0; k0 < CC; k0 += 32) {
    {
      const float* ap = A + (size_t)(mbase + sr) * CC + k0 + sc0;
      f32x4 f0 = *(const f32x4*)ap;
      f32x4 f1 = *(const f32x4*)(ap + 4);
      bf16x8 va;
#pragma unroll
      for (int i = 0; i < 4; i++) {
        va[i] = (short)f2bf(f0[i]);
        va[i + 4] = (short)f2bf(f1[i]);
      }
      *(bf16x8*)&As[sr * 40 + sc0] = va;

      const float* bp = W + (size_t)(nbase + sr) * CC + k0 + sc0;
      f32x4 g0 = *(const f32x4*)bp;
      f32x4 g1 = *(const f32x4*)(bp + 4);
      bf16x8 vb;
#pragma unroll
      for (int i = 0; i < 4; i++) {
        vb[i] = (short)f2bf(g0[i]);
        vb[i + 4] = (short)f2bf(g1[i]);
      }
      *(bf16x8*)&Bs[sr * 40 + sc0] = vb;
    }
    __syncthreads();

    bf16x8 a0 = *(const bf16x8*)&As[(wm * 32 + l15) * 40 + lhi * 8];
    bf16x8 a1 = *(const bf16x8*)&As[(wm * 32 + 16 + l15) * 40 + lhi * 8];
    bf16x8 b0 = *(const bf16x8*)&Bs[(wn * 32 + l15) * 40 + lhi * 8];
    bf16x8 b1 = *(const bf16x8*)&Bs[(wn * 32 + 16 + l15) * 40 + lhi * 8];
    acc[0][0] = mfma16(a0, b0, acc[0][0]);
    acc[0][1] = mfma16(a0, b1, acc[0][1]);
    acc[1][0] = mfma16(a1, b0, acc[1][0]);
    acc[1][1] = mfma16(a1, b1, acc[1][1]);
    __syncthreads();
  }

#pragma unroll
  for (int mi = 0; mi < 2; mi++)
#pragma unroll
    for (int ni = 0; ni < 2; ni++)
#pragma unroll
      for (int r = 0; r < 4; r++) {
        int grow = mbase + wm * 32 + mi * 16 + 4 * lhi + r;
        int gcol = nbase + wn * 32 + ni * 16 + l15;
        float val = acc[mi][ni][r] + bias[gcol];
        if (MODE == 0) {
          int T = 1 << tlog2;
          int bq = grow >> tlog2, tt = grow & (T - 1);
          int h = gcol >> 6, d = gcol & 63;
          size_t oidx = ((size_t)(bq * NH + h) * T + tt) * HD + d;
          ((unsigned short*)outp)[oidx] = f2bf(val);
        } else {
          ((float*)outp)[(size_t)grow * CC + gcol] = val;
        }
      }
}

// ---------------------------------------------------------------------------
// Flash attention fwd. Block = 4 waves, each wave owns a 16-row q-tile of the
// same (b,h); iterates 64-key tiles with online softmax fully in registers.
// Writes y_pre (fp32, (b,t,c)) and per-row running max m / inverse-sum 1/l.
// ---------------------------------------------------------------------------
__global__ __launch_bounds__(256) void attn_fwd(
    const unsigned short* __restrict__ Qw, const unsigned short* __restrict__ Kw,
    const unsigned short* __restrict__ Vw, float* __restrict__ y_pre,
    float* __restrict__ m_ws, float* __restrict__ il_ws) {
  // vt stride 72 shorts (=144B = 9x16B): k spans 0..63, stride must exceed 64;
  // 144B keeps b128 reads 16B-aligned; rows 36 words apart = 4 banks -> 8-bank spread
  __shared__ __align__(16) unsigned short vt[64 * 72];        // V tile transposed [d][k]
  __shared__ __align__(16) unsigned short plds[4][16 * 72];   // per-wave P tiles [row][key]

  const int tid = threadIdx.x;
  const int wid = tid >> 6, l = tid & 63, l15 = l & 15, lhi = l >> 4;
  const int qg = blockIdx.x, h = blockIdx.y, b = blockIdx.z;
  const int qbase = qg * 64 + wid * 16;

  const unsigned short* Qh = Qw + (size_t)(b * NH + h) * TX * HD;
  const unsigned short* Kh = Kw + (size_t)(b * NH + h) * TC * HD;
  const unsigned short* Vh = Vw + (size_t)(b * NH + h) * TC * HD;

  // Q A-frags (constant over the whole K loop): row=l15, k=8*lhi+e (+32 for second half)
  bf16x8 aq0 = *(const bf16x8*)(Qh + (size_t)(qbase + l15) * HD + lhi * 8);
  bf16x8 aq1 = *(const bf16x8*)(Qh + (size_t)(qbase + l15) * HD + 32 + lhi * 8);

  f32x4 accy[4];
#pragma unroll
  for (int db = 0; db < 4; db++) accy[db] = zero4();
  float mrun[4], lrun[4];
#pragma unroll
  for (int r = 0; r < 4; r++) { mrun[r] = -1e30f; lrun[r] = 0.f; }

  const int vr = tid >> 3, vj = tid & 7, vd0 = vj * 8;

  for (int kt = 0; kt < TC / 64; kt++) {
    const int keyb = kt * 64;

    // stage V tile transposed (global read coalesced; stagger kills bank conflicts)
#pragma unroll
    for (int rr = 0; rr < 64; rr += 32) {
      bf16x8 v = *(const bf16x8*)(Vh + (size_t)(keyb + vr + rr) * HD + vd0);
#pragma unroll
      for (int i = 0; i < 8; i++) {
        int j = (i + vj) & 7;
        vt[(vd0 + j) * 72 + (vr + rr)] = (unsigned short)v[j];
      }
    }

    // QK^T for 4 key-blocks of 16 (K frags straight from global, L1/L2 hot)
    f32x4 s[4];
#pragma unroll
    for (int kb = 0; kb < 4; kb++) {
      const unsigned short* kp = Kh + (size_t)(keyb + kb * 16 + l15) * HD + lhi * 8;
      bf16x8 bk0 = *(const bf16x8*)kp;
      bf16x8 bk1 = *(const bf16x8*)(kp + 32);
      f32x4 a = zero4();
      a = mfma16(aq0, bk0, a);
      a = mfma16(aq1, bk1, a);
      s[kb] = a * 0.125f;  // 1/sqrt(64)
    }

    // online softmax update; rows of reg r live on the 16 lanes of each lhi group
    float mnew[4], scal[4], psum[4];
#pragma unroll
    for (int r = 0; r < 4; r++) {
      float mx = fmaxf(fmaxf(s[0][r], s[1][r]), fmaxf(s[2][r], s[3][r]));
#pragma unroll
      for (int off = 1; off < 16; off <<= 1) mx = fmaxf(mx, __shfl_xor(mx, off));
      mnew[r] = fmaxf(mrun[r], mx);
      scal[r] = __expf(mrun[r] - mnew[r]);
      psum[r] = 0.f;
    }
#pragma unroll
    for (int kb = 0; kb < 4; kb++)
#pragma unroll
      for (int r = 0; r < 4; r++) {
        float p = __expf(s[kb][r] - mnew[r]);
        psum[r] += p;
        plds[wid][(4 * lhi + r) * 72 + kb * 16 + l15] = f2bf(p);
      }
#pragma unroll
    for (int r = 0; r < 4; r++) {
      float ps = psum[r];
#pragma unroll
      for (int off = 1; off < 16; off <<= 1) ps += __shfl_xor(ps, off);
      lrun[r] = lrun[r] * scal[r] + ps;
      mrun[r] = mnew[r];
    }

    __syncthreads();  // vt + plds writes visible

    // rescale accumulator by exp(m_old - m_new)
#pragma unroll
    for (int db = 0; db < 4; db++)
#pragma unroll
      for (int r = 0; r < 4; r++) accy[db][r] *= scal[r];

    // PV: A = P tile (via LDS transpose), B = V tile (transposed in LDS)
    bf16x8 ap0 = *(const bf16x8*)&plds[wid][l15 * 72 + lhi * 8];
    bf16x8 ap1 = *(const bf16x8*)&plds[wid][l15 * 72 + 32 + lhi * 8];
#pragma unroll
    for (int db = 0; db < 4; db++) {
      bf16x8 bv0 = *(const bf16x8*)&vt[(db * 16 + l15) * 72 + lhi * 8];
      bf16x8 bv1 = *(const bf16x8*)&vt[(db * 16 + l15) * 72 + 32 + lhi * 8];
      accy[db] = mfma16(ap0, bv0, accy[db]);
      accy[db] = mfma16(ap1, bv1, accy[db]);
    }
    __syncthreads();  // all reads done before next stage overwrites vt
  }

  float il[4];
#pragma unroll
  for (int r = 0; r < 4; r++) il[r] = 1.f / lrun[r];

#pragma unroll
  for (int db = 0; db < 4; db++)
#pragma unroll
    for (int r = 0; r < 4; r++) {
      int trow = qbase + 4 * lhi + r;
      y_pre[(size_t)(b * TX + trow) * CC + h * HD + db * 16 + l15] = accy[db][r] * il[r];
    }
  if (l15 == 0) {
#pragma unroll
    for (int r = 0; r < 4; r++) {
      int idx = (b * NH + h) * TX + qbase + 4 * lhi + r;
      m_ws[idx] = mrun[r];
      il_ws[idx] = il[r];
    }
  }
}

// ---------------------------------------------------------------------------
// att_mean v2: recompute QK^T per head, p = exp(s - m) * (1/l), mean over heads.
// Block: 16 q-rows x 256 keys (wave w -> 64-key slice). Head loop is fully
// unrolled with double-buffered register prefetch (Q frags, 8 K frags, m/il
// f32x4) so the next head's loads are in flight during current head's
// MFMA+exp work. All buffer indices compile-time (h&1) to stay in registers.
// ---------------------------------------------------------------------------
__global__ __launch_bounds__(256) void att_mean_k(
    const unsigned short* __restrict__ Qw, const unsigned short* __restrict__ Kw,
    const float* __restrict__ m_ws, const float* __restrict__ il_ws,
    float* __restrict__ attm) {
  const int tid = threadIdx.x;
  const int wid = tid >> 6, l = tid & 63, l15 = l & 15, lhi = l >> 4;
  const int keyb = blockIdx.x * 256 + wid * 64;
  const int qbase = blockIdx.y * 16;
  const int b = blockIdx.z;

  const unsigned short* Qb = Qw + (size_t)b * NH * TX * HD;
  const unsigned short* Kb = Kw + (size_t)b * NH * TC * HD;

  bf16x8 aq0[2], aq1[2], bk0[2][4], bk1[2][4];
  f32x4 mm[2], ii[2];

  auto load_head = [&](int h, int p) {
    const unsigned short* qp = Qb + (size_t)h * TX * HD + (size_t)(qbase + l15) * HD + lhi * 8;
    aq0[p] = *(const bf16x8*)qp;
    aq1[p] = *(const bf16x8*)(qp + 32);
#pragma unroll
    for (int kb = 0; kb < 4; kb++) {
      const unsigned short* kp =
          Kb + (size_t)h * TC * HD + (size_t)(keyb + kb * 16 + l15) * HD + lhi * 8;
      bk0[p][kb] = *(const bf16x8*)kp;
      bk1[p][kb] = *(const bf16x8*)(kp + 32);
    }
    mm[p] = *(const f32x4*)(m_ws + (size_t)(b * NH + h) * TX + qbase + 4 * lhi);
    ii[p] = *(const f32x4*)(il_ws + (size_t)(b * NH + h) * TX + qbase + 4 * lhi);
  };

  f32x4 am[4];
#pragma unroll
  for (int kb = 0; kb < 4; kb++) am[kb] = zero4();

  load_head(0, 0);
#pragma unroll
  for (int h = 0; h < NH; h++) {
    const int p = h & 1;
    if (h + 1 < NH) load_head(h + 1, p ^ 1);  // prefetch next head
#pragma unroll
    for (int kb = 0; kb < 4; kb++) {
      f32x4 a = zero4();
      a = mfma16(aq0[p], bk0[p][kb], a);
      a = mfma16(aq1[p], bk1[p][kb], a);
#pragma unroll
      for (int r = 0; r < 4; r++)
        am[kb][r] += __expf(a[r] * 0.125f - mm[p][r]) * ii[p][r];
    }
  }

#pragma unroll
  for (int kb = 0; kb < 4; kb++)
#pragma unroll
    for (int r = 0; r < 4; r++) {
      int trow = qbase + 4 * lhi + r;
      attm[(size_t)(b * TX + trow) * TC + keyb + kb * 16 + l15] = am[kb][r] * 0.125f;
    }
}

// ---------------------------------------------------------------------------
extern "C" void kernel_launch(void* const* d_in, const int* in_sizes, int n_in,
                              void* d_out, int out_size, void* d_ws, size_t ws_size,
                              hipStream_t stream) {
  const float* x   = (const float*)d_in[0];
  const float* ctx = (const float*)d_in[1];
  const float* Wq  = (const float*)d_in[2];
  const float* bq  = (const float*)d_in[3];
  const float* Wk  = (const float*)d_in[4];
  const float* bk  = (const float*)d_in[5];
  const float* Wv  = (const float*)d_in[6];
  const float* bv  = (const float*)d_in[7];
  const float* Wo  = (const float*)d_in[8];
  const float* bo  = (const float*)d_in[9];

  float* y_out = (float*)d_out;                       // (B, Tx, C)
  float* attm  = y_out + (size_t)Bb * TX * CC;        // (B, Tx, Tc)

  // workspace layout (all 16B-aligned): ~56.5 MB
  unsigned short* q_ws = (unsigned short*)d_ws;                  // B*NH*TX*HD bf16
  unsigned short* k_ws = q_ws + (size_t)Bb * NH * TX * HD;       // B*NH*TC*HD bf16
  unsigned short* v_ws = k_ws + (size_t)Bb * NH * TC * HD;       // B*NH*TC*HD bf16
  float* m_ws  = (float*)(v_ws + (size_t)Bb * NH * TC * HD);     // B*NH*TX f32
  float* il_ws = m_ws + (size_t)Bb * NH * TX;                    // B*NH*TX f32
  float* y_pre = il_ws + (size_t)Bb * NH * TX;                   // B*TX*CC f32

  proj_gemm<0><<<dim3(CC / 64, (Bb * TX) / 64), 256, 0, stream>>>(x, Wq, bq, q_ws, 10);
  proj_gemm<0><<<dim3(CC / 64, (Bb * TC) / 64), 256, 0, stream>>>(ctx, Wk, bk, k_ws, 11);
  proj_gemm<0><<<dim3(CC / 64, (Bb * TC) / 64), 256, 0, stream>>>(ctx, Wv, bv, v_ws, 11);
  attn_fwd<<<dim3(TX / 64, NH, Bb), 256, 0, stream>>>(q_ws, k_ws, v_ws, y_pre, m_ws, il_ws);
  att_mean_k<<<dim3(TC / 256, TX / 16, Bb), 256, 0, stream>>>(q_ws, k_ws, m_ws, il_ws, attm);
  proj_gemm<1><<<dim3(CC / 64, (Bb * TX) / 64), 256, 0, stream>>>(y_pre, Wo, bo, y_out, 10);
}